// Round 3
// baseline (767.513 us; speedup 1.0000x reference)
//
#include <hip/hip_runtime.h>

// TransitionUp: segment mean-pool -> linear2+ReLU (tiny) -> broadcast ->
// [x, h[seg]] @ W1 + b1 -> BN(eval) -> ReLU.
//
// Folded math:
//   a[j]     = gamma[j] * rsqrt(run_var[j]+eps)
//   d[j]     = beta[j] - run_mean[j]*a[j]
//   W'[k][j] = W1[k][j] * a[j]                  (k in 0..63, the x-half)
//   bias'[b][j] = (h[b]@W1[64:] + b1)[j]*a[j] + d[j]
//   out[p][j] = relu( x[p]@W'[:,j] + bias'[seg(p)][j] )
//
// R2: main kernel is MFMA f16 16x16x32, NO LDS; B pinned in 32 VGPRs.
// R3: LLC-residency games (reverse rescan + NT out stores) = exactly neutral
//     -> LLC does not retain a 256 MiB working set across kernels.
// R4: f16 z-roundtrip REGRESSED +36us. Root cause: NONTEMPORAL x loads on a
//     16B-granule/16B-gap pattern defeat L1/L2 line reuse -> ~2x x-read
//     traffic. Lesson: NT hints only on fully-contiguous streams; the
//     roundtrip has no traffic upside anyway (804 MB either way). REVERTED.
// R5 (this round): R3 kernels verbatim, but mid_kernel is folded into the
//     LAST pool block via an atomic completion ticket (saves one dispatch +
//     one inter-kernel drain). gsums read back with agent-scope atomic loads
//     (bypasses potentially-stale per-XCD caches; atomicAdds land at the
//     coherent point). main_kernel is byte-identical to the 521.97us twin.

#define MAXB 16

typedef _Float16 half8 __attribute__((ext_vector_type(8)));
typedef float float4v __attribute__((ext_vector_type(4)));

// ---------------------------------------------------------------- kernel 1
// Per-segment column sums of x into gsums[B][64] (pre-zeroed via memset).
// Fast path: block's whole point range in one segment -> branch-free loop.
// Tail: completion ticket; the last block to finish runs the "mid" phase
// (mean -> h -> bias', and WpT = f16(W1[:64]^T * a)) entirely in-block.
__global__ __launch_bounds__(256) void pool_kernel(
    const float* __restrict__ x, const int* __restrict__ o,
    const float* __restrict__ W2, const float* __restrict__ b2,
    const float* __restrict__ W1, const float* __restrict__ b1,
    const float* __restrict__ gamma, const float* __restrict__ beta,
    const float* __restrict__ rmean, const float* __restrict__ rvar,
    float* __restrict__ gsums, float* __restrict__ biasp,
    _Float16* __restrict__ WpT, int* __restrict__ ticket,
    int nB, int ptsPerBlock, int nBlocks) {
  __shared__ int so_s[MAXB];
  __shared__ float red[16 * 64];      // fast-path reduction scratch / smean
  __shared__ float ssum2[MAXB * 64];  // slow-path bins / sh
  __shared__ int lastf;
  const int tid = threadIdx.x;
  if (tid < nB) so_s[tid] = o[tid];
  __syncthreads();

  const int c4 = (tid & 15) * 4;  // 4 consecutive columns per thread
  const int r  = tid >> 4;        // 16 rows per 256 threads
  const int p0 = blockIdx.x * ptsPerBlock;
  const int iters = ptsPerBlock >> 4;

  int sFirst = 0;
  while (p0 >= so_s[sFirst]) sFirst++;
  int sLast = sFirst;
  while (p0 + ptsPerBlock - 1 >= so_s[sLast]) sLast++;

  if (sFirst == sLast) {  // block-uniform branch
    float a0 = 0.f, a1 = 0.f, a2 = 0.f, a3 = 0.f;
    const float* xp = x + (size_t)(p0 + r) * 64 + c4;
#pragma unroll 4
    for (int i = 0; i < iters; ++i) {
      float4 v = *(const float4*)(xp + (size_t)i * 1024);
      a0 += v.x; a1 += v.y; a2 += v.z; a3 += v.w;
    }
    float4 t = {a0, a1, a2, a3};
    *(float4*)&red[r * 64 + c4] = t;
    __syncthreads();
    if (tid < 64) {
      float s = 0.f;
#pragma unroll
      for (int rr = 0; rr < 16; ++rr) s += red[rr * 64 + tid];
      atomicAdd(&gsums[sFirst * 64 + tid], s);
    }
  } else {  // boundary block (rare): per-point binning
    for (int i = tid; i < nB * 64; i += 256) ssum2[i] = 0.f;
    __syncthreads();
    for (int i = 0; i < iters; ++i) {
      int p = p0 + i * 16 + r;
      int s = 0;
      while (p >= so_s[s]) s++;
      float4 v = *(const float4*)(x + (size_t)p * 64 + c4);
      atomicAdd(&ssum2[s * 64 + c4 + 0], v.x);
      atomicAdd(&ssum2[s * 64 + c4 + 1], v.y);
      atomicAdd(&ssum2[s * 64 + c4 + 2], v.z);
      atomicAdd(&ssum2[s * 64 + c4 + 3], v.w);
    }
    __syncthreads();
    for (int i = tid; i < nB * 64; i += 256) {
      float v = ssum2[i];
      if (v != 0.f) atomicAdd(&gsums[i], v);
    }
  }

  // ---- completion ticket: last block runs the mid phase ----
  __threadfence();  // make this block's gsums atomics globally visible
  __syncthreads();
  if (tid == 0) lastf = (atomicAdd(ticket, 1) == nBlocks - 1) ? 1 : 0;
  __syncthreads();
  if (!lastf) return;
  __threadfence();

  float* smean = red;    // reuse LDS (both paths are past their last use)
  float* sh    = ssum2;
  const int j = tid & 63;
  const int bq = tid >> 6;

  for (int i = tid; i < nB * 64; i += 256) {
    int b = i >> 6;
    int cnt = so_s[b] - (b ? so_s[b - 1] : 0);
    float g = __hip_atomic_load(&gsums[i], __ATOMIC_RELAXED,
                                __HIP_MEMORY_SCOPE_AGENT);
    smean[i] = g / (float)cnt;
  }
  __syncthreads();

  for (int b = bq; b < nB; b += 4) {
    float p0f = 0.f, p1 = 0.f, p2 = 0.f, p3 = 0.f;  // 4 chains for ILP
#pragma unroll
    for (int c = 0; c < 64; c += 4) {
      p0f = fmaf(smean[b * 64 + c + 0], W2[(c + 0) * 64 + j], p0f);
      p1  = fmaf(smean[b * 64 + c + 1], W2[(c + 1) * 64 + j], p1);
      p2  = fmaf(smean[b * 64 + c + 2], W2[(c + 2) * 64 + j], p2);
      p3  = fmaf(smean[b * 64 + c + 3], W2[(c + 3) * 64 + j], p3);
    }
    sh[b * 64 + j] = fmaxf(((p0f + p1) + (p2 + p3)) + b2[j], 0.f);
  }
  __syncthreads();

  const float a = gamma[j] * rsqrtf(rvar[j] + 1e-5f);
  const float d = beta[j] - rmean[j] * a;
  for (int b = bq; b < nB; b += 4) {
    float p0f = 0.f, p1 = 0.f, p2 = 0.f, p3 = 0.f;
#pragma unroll
    for (int c = 0; c < 64; c += 4) {
      p0f = fmaf(sh[b * 64 + c + 0], W1[(64 + c + 0) * 64 + j], p0f);
      p1  = fmaf(sh[b * 64 + c + 1], W1[(64 + c + 1) * 64 + j], p1);
      p2  = fmaf(sh[b * 64 + c + 2], W1[(64 + c + 2) * 64 + j], p2);
      p3  = fmaf(sh[b * 64 + c + 3], W1[(64 + c + 3) * 64 + j], p3);
    }
    biasp[b * 64 + j] = (((p0f + p1) + (p2 + p3)) + b1[j]) * a + d;
  }
  for (int k = bq * 16; k < bq * 16 + 16; ++k)
    WpT[j * 64 + k] = (_Float16)(W1[k * 64 + j] * a);
}

// ---------------------------------------------------------------- kernel 2
// Each wave: 8 row-tiles of 16 points, 4 col-tiles of 16. No LDS, no barrier.
// A frag (m89 layout): lane holds A[m=lane&15][k=quad*8+j], fp32->f16 cvt.
// B frag: lane holds B[k=quad*8+j][n=lane&15] from WpT[n][k] (contiguous).
// Byte-identical to the measured-best 521.97us version.
__global__ __launch_bounds__(256) void main_kernel(
    const float* __restrict__ x, const int* __restrict__ o,
    const _Float16* __restrict__ WpT, const float* __restrict__ biasp,
    float* __restrict__ out, int nB) {
  const int lane = threadIdx.x & 63;
  const int m = lane & 15;
  const int quad = lane >> 4;
  const int rows0 = (blockIdx.x * 4 + (threadIdx.x >> 6)) * 128;

  // B = W' pinned in registers: 4 col-tiles x 2 K-halves x 8 f16
  half8 bfrag[4][2];
#pragma unroll
  for (int t = 0; t < 4; ++t)
#pragma unroll
    for (int h = 0; h < 2; ++h)
      bfrag[t][h] = *(const half8*)(WpT + (t * 16 + m) * 64 + h * 32 + quad * 8);

  // lane m holds o[m] for ballot-based segment lookup
  const int ov = (m < nB) ? o[m] : 0x7fffffff;

  float4 f0, f1, f2, f3;  // fp32 staging for one 16x64 A-tile (this lane: 16 floats)
  {
    const float* p = x + (size_t)(rows0 + m) * 64 + quad * 8;
    f0 = *(const float4*)(p + 0);
    f1 = *(const float4*)(p + 4);
    f2 = *(const float4*)(p + 32);
    f3 = *(const float4*)(p + 36);
  }

  for (int i = 0; i < 8; ++i) {
    const int row0 = rows0 + i * 16;
    // cvt staging -> f16 fragments (k 0..31 and 32..63)
    half8 a0, a1;
    a0[0] = (_Float16)f0.x; a0[1] = (_Float16)f0.y;
    a0[2] = (_Float16)f0.z; a0[3] = (_Float16)f0.w;
    a0[4] = (_Float16)f1.x; a0[5] = (_Float16)f1.y;
    a0[6] = (_Float16)f1.z; a0[7] = (_Float16)f1.w;
    a1[0] = (_Float16)f2.x; a1[1] = (_Float16)f2.y;
    a1[2] = (_Float16)f2.z; a1[3] = (_Float16)f2.w;
    a1[4] = (_Float16)f3.x; a1[5] = (_Float16)f3.y;
    a1[6] = (_Float16)f3.z; a1[7] = (_Float16)f3.w;

    if (i < 7) {  // prefetch next tile while MFMA+stores run
      const float* p = x + (size_t)(row0 + 16 + m) * 64 + quad * 8;
      f0 = *(const float4*)(p + 0);
      f1 = *(const float4*)(p + 4);
      f2 = *(const float4*)(p + 32);
      f3 = *(const float4*)(p + 36);
    }

    // segment of this 16-row tile via ballot popcount (o in lanes 0..15)
    const int s0 = (int)__popcll(__ballot(row0 >= ov) & 0xFFFFull);
    const int s1 = (int)__popcll(__ballot(row0 + 15 >= ov) & 0xFFFFull);

    if (s0 == s1) {  // tile entirely in one segment (common)
      const float* bp = biasp + s0 * 64 + m;
#pragma unroll
      for (int t = 0; t < 4; ++t) {
        float4v c = {0.f, 0.f, 0.f, 0.f};
        c = __builtin_amdgcn_mfma_f32_16x16x32_f16(a0, bfrag[t][0], c, 0, 0, 0);
        c = __builtin_amdgcn_mfma_f32_16x16x32_f16(a1, bfrag[t][1], c, 0, 0, 0);
        const float bv = bp[t * 16];
        float* op = out + (size_t)(row0 + quad * 4) * 64 + t * 16 + m;
#pragma unroll
        for (int rg = 0; rg < 4; ++rg)
          op[(size_t)rg * 64] = fmaxf(c[rg] + bv, 0.f);
      }
    } else {  // boundary tile (rare): per-row segment scan
#pragma unroll
      for (int t = 0; t < 4; ++t) {
        float4v c = {0.f, 0.f, 0.f, 0.f};
        c = __builtin_amdgcn_mfma_f32_16x16x32_f16(a0, bfrag[t][0], c, 0, 0, 0);
        c = __builtin_amdgcn_mfma_f32_16x16x32_f16(a1, bfrag[t][1], c, 0, 0, 0);
#pragma unroll
        for (int rg = 0; rg < 4; ++rg) {
          const int row = row0 + quad * 4 + rg;
          int s = 0;
          for (int q2 = 0; q2 < nB; ++q2) s += (row >= o[q2]) ? 1 : 0;
          const float bv = biasp[s * 64 + t * 16 + m];
          out[(size_t)row * 64 + t * 16 + m] = fmaxf(c[rg] + bv, 0.f);
        }
      }
    }
  }
}

// ---------------------------------------------------------------- launch
extern "C" void kernel_launch(void* const* d_in, const int* in_sizes, int n_in,
                              void* d_out, int out_size, void* d_ws, size_t ws_size,
                              hipStream_t stream) {
  const float* x     = (const float*)d_in[0];
  const int*   o     = (const int*)d_in[1];
  const float* W2    = (const float*)d_in[2];
  const float* b2    = (const float*)d_in[3];
  const float* W1    = (const float*)d_in[4];
  const float* b1    = (const float*)d_in[5];
  const float* gamma = (const float*)d_in[6];
  const float* beta  = (const float*)d_in[7];
  const float* rmean = (const float*)d_in[8];
  const float* rvar  = (const float*)d_in[9];
  float* out = (float*)d_out;

  const int npts = in_sizes[0] / 64;
  const int nB   = in_sizes[1];

  // ws layout: [gsums 4096B][ticket 4B + pad 60B][biasp 4096B][WpT 8192B]
  float*    gsums  = (float*)d_ws;
  int*      ticket = (int*)((char*)d_ws + 4096);
  float*    biasp  = (float*)((char*)d_ws + 4160);
  _Float16* WpT    = (_Float16*)((char*)d_ws + 8256);

  hipMemsetAsync(d_ws, 0, 4160, stream);  // gsums + ticket

  const int blocks1 = 2048;  // 512 pts/block at N=1M
  pool_kernel<<<blocks1, 256, 0, stream>>>(
      x, o, W2, b2, W1, b1, gamma, beta, rmean, rvar,
      gsums, biasp, WpT, ticket, nB, npts / blocks1, blocks1);
  main_kernel<<<npts / 512, 256, 0, stream>>>(x, o, WpT, biasp, out, nB);
}

// Round 4
// 525.305 us; speedup vs baseline: 1.4611x; 1.4611x over previous
//
#include <hip/hip_runtime.h>

// TransitionUp: segment mean-pool -> linear2+ReLU (tiny) -> broadcast ->
// [x, h[seg]] @ W1 + b1 -> BN(eval) -> ReLU.
//
// Folded math:
//   a[j]     = gamma[j] * rsqrt(run_var[j]+eps)
//   d[j]     = beta[j] - run_mean[j]*a[j]
//   W'[k][j] = W1[k][j] * a[j]                  (k in 0..63, the x-half)
//   bias'[b][j] = (h[b]@W1[64:] + b1)[j]*a[j] + d[j]
//   out[p][j] = relu( x[p]@W'[:,j] + bias'[seg(p)][j] )
//
// Session ledger:
// R2: main = MFMA f16 16x16x32, NO LDS; B pinned in 32 VGPRs.  -> 521.97us
// R3: LLC games (reverse rescan + NT out) exactly neutral -> LLC does not
//     retain a 256MiB set across kernels by scan-order tricks.
// R4: f16 z-roundtrip REGRESSED +36us: NT x loads on a gappy 16B pattern
//     defeat line reuse (~2x x traffic). NT only on contiguous streams.
// R5: ticket + per-block __threadfence() REGRESSED +245us: device-scope
//     fence per block writes back the (non-coherent) per-XCD L2; 2048 of
//     them serialize the TCC (pool: 4.3% BW, 0.56% VALU). NEVER fence
//     per-block on CDNA4; kernel boundaries are the only cheap ordering.
//     Useful datum: pool FETCH=134MB (half of x) -> LLC serves ~50% of the
//     rescan; effective HBM floor ~536MB + 326us fixed harness fills.
// R6 (this round): pool & main-loop reverted to the R0 twins verbatim; mid
//     folded into main as a REDUNDANT PER-BLOCK PROLOGUE (no fence needed:
//     stream order makes gsums visible). bias' in LDS, W' fragments built
//     in-register from W1 (R4-K1 proven pattern). Saves 1 dispatch + 2
//     inter-kernel bubbles + single-block mid latency; costs ~3-4us of
//     hidden redundant VALU. Numerics op-identical to R0.

#define MAXB 16

typedef _Float16 half8 __attribute__((ext_vector_type(8)));
typedef float float4v __attribute__((ext_vector_type(4)));

// ---------------------------------------------------------------- kernel 1
// Per-segment column sums of x into gsums[B][64] (pre-zeroed via memset).
// R0 verbatim (the 521.97us twin). No fence, no ticket.
__global__ __launch_bounds__(256) void pool_kernel(
    const float* __restrict__ x, const int* __restrict__ o,
    float* __restrict__ gsums, int nB, int ptsPerBlock) {
  __shared__ int so_s[MAXB];
  __shared__ float red[16 * 64];      // fast-path reduction scratch
  __shared__ float ssum2[MAXB * 64];  // slow-path bins
  const int tid = threadIdx.x;
  if (tid < nB) so_s[tid] = o[tid];
  __syncthreads();

  const int c4 = (tid & 15) * 4;  // 4 consecutive columns per thread
  const int r  = tid >> 4;        // 16 rows per 256 threads
  const int p0 = blockIdx.x * ptsPerBlock;
  const int iters = ptsPerBlock >> 4;

  int sFirst = 0;
  while (p0 >= so_s[sFirst]) sFirst++;
  int sLast = sFirst;
  while (p0 + ptsPerBlock - 1 >= so_s[sLast]) sLast++;

  if (sFirst == sLast) {  // block-uniform branch
    float a0 = 0.f, a1 = 0.f, a2 = 0.f, a3 = 0.f;
    const float* xp = x + (size_t)(p0 + r) * 64 + c4;
#pragma unroll 4
    for (int i = 0; i < iters; ++i) {
      float4 v = *(const float4*)(xp + (size_t)i * 1024);
      a0 += v.x; a1 += v.y; a2 += v.z; a3 += v.w;
    }
    float4 t = {a0, a1, a2, a3};
    *(float4*)&red[r * 64 + c4] = t;
    __syncthreads();
    if (tid < 64) {
      float s = 0.f;
#pragma unroll
      for (int rr = 0; rr < 16; ++rr) s += red[rr * 64 + tid];
      atomicAdd(&gsums[sFirst * 64 + tid], s);
    }
  } else {  // boundary block (rare): per-point binning
    for (int i = tid; i < nB * 64; i += 256) ssum2[i] = 0.f;
    __syncthreads();
    for (int i = 0; i < iters; ++i) {
      int p = p0 + i * 16 + r;
      int s = 0;
      while (p >= so_s[s]) s++;
      float4 v = *(const float4*)(x + (size_t)p * 64 + c4);
      atomicAdd(&ssum2[s * 64 + c4 + 0], v.x);
      atomicAdd(&ssum2[s * 64 + c4 + 1], v.y);
      atomicAdd(&ssum2[s * 64 + c4 + 2], v.z);
      atomicAdd(&ssum2[s * 64 + c4 + 3], v.w);
    }
    __syncthreads();
    for (int i = tid; i < nB * 64; i += 256) {
      float v = ssum2[i];
      if (v != 0.f) atomicAdd(&gsums[i], v);
    }
  }
}

// ---------------------------------------------------------------- kernel 2
// Prologue (redundant per block, ~0.35us hidden under streaming):
//   smean = gsums/cnt -> h = relu(smean@W2+b2) -> bias'（LDS) ;
//   bfrag = f16(W1[:64]*a) built in-register (no WpT buffer).
// Hot loop: R0 verbatim (8 row-tiles x 4 col-tiles, MFMA, no extra barrier).
__global__ __launch_bounds__(256) void main_kernel(
    const float* __restrict__ x, const int* __restrict__ o,
    const float* __restrict__ W2, const float* __restrict__ b2,
    const float* __restrict__ W1, const float* __restrict__ b1,
    const float* __restrict__ gamma, const float* __restrict__ beta,
    const float* __restrict__ rmean, const float* __restrict__ rvar,
    const float* __restrict__ gsums, float* __restrict__ out, int nB) {
  __shared__ float bufA[MAXB * 64];  // smean, then bias' (overlaid)
  __shared__ float bufB[MAXB * 64];  // sh
  const int tid = threadIdx.x;
  const int lane = tid & 63;
  const int m = lane & 15;
  const int quad = lane >> 4;
  const int rows0 = (blockIdx.x * 4 + (tid >> 6)) * 128;

  // Issue the first x-tile loads IMMEDIATELY so HBM streaming starts before
  // the prologue compute (loads complete under ~700 VALU ops of prologue).
  float4 f0, f1, f2, f3;
  {
    const float* p = x + (size_t)(rows0 + m) * 64 + quad * 8;
    f0 = *(const float4*)(p + 0);
    f1 = *(const float4*)(p + 4);
    f2 = *(const float4*)(p + 32);
    f3 = *(const float4*)(p + 36);
  }

  // ---- prologue: per-block mid phase (numerics identical to old mid) ----
  const int j = tid & 63;
  const int bq = tid >> 6;

  for (int i = tid; i < nB * 64; i += 256) {
    int b = i >> 6;
    int cnt = o[b] - (b ? o[b - 1] : 0);
    bufA[i] = gsums[i] / (float)cnt;  // smean (gsums complete: stream order)
  }
  __syncthreads();

  for (int b = bq; b < nB; b += 4) {
    float p0f = 0.f, p1 = 0.f, p2 = 0.f, p3 = 0.f;  // 4 chains for ILP
#pragma unroll
    for (int c = 0; c < 64; c += 4) {
      p0f = fmaf(bufA[b * 64 + c + 0], W2[(c + 0) * 64 + j], p0f);
      p1  = fmaf(bufA[b * 64 + c + 1], W2[(c + 1) * 64 + j], p1);
      p2  = fmaf(bufA[b * 64 + c + 2], W2[(c + 2) * 64 + j], p2);
      p3  = fmaf(bufA[b * 64 + c + 3], W2[(c + 3) * 64 + j], p3);
    }
    bufB[b * 64 + j] = fmaxf(((p0f + p1) + (p2 + p3)) + b2[j], 0.f);  // h
  }
  __syncthreads();

  const float aj = gamma[j] * rsqrtf(rvar[j] + 1e-5f);
  const float dj = beta[j] - rmean[j] * aj;
  for (int b = bq; b < nB; b += 4) {
    float p0f = 0.f, p1 = 0.f, p2 = 0.f, p3 = 0.f;
#pragma unroll
    for (int c = 0; c < 64; c += 4) {
      p0f = fmaf(bufB[b * 64 + c + 0], W1[(64 + c + 0) * 64 + j], p0f);
      p1  = fmaf(bufB[b * 64 + c + 1], W1[(64 + c + 1) * 64 + j], p1);
      p2  = fmaf(bufB[b * 64 + c + 2], W1[(64 + c + 2) * 64 + j], p2);
      p3  = fmaf(bufB[b * 64 + c + 3], W1[(64 + c + 3) * 64 + j], p3);
    }
    // write bias' into bufA (smean dead; stage2 reads only bufB) — no race
    bufA[b * 64 + j] = (((p0f + p1) + (p2 + p3)) + b1[j]) * aj + dj;
  }

  // B = W' built in-register: 4 col-tiles x 2 K-halves x 8 f16 (R4-K1 pattern)
  half8 bfrag[4][2];
#pragma unroll
  for (int t = 0; t < 4; ++t) {
    const int n = t * 16 + m;
    const float an = gamma[n] * rsqrtf(rvar[n] + 1e-5f);
#pragma unroll
    for (int h = 0; h < 2; ++h)
#pragma unroll
      for (int jj = 0; jj < 8; ++jj)
        bfrag[t][h][jj] = (_Float16)(W1[(h * 32 + quad * 8 + jj) * 64 + n] * an);
  }
  __syncthreads();  // bias' (bufA) visible to all waves before the hot loop

  // lane m holds o[m] for ballot-based segment lookup
  const int ov = (m < nB) ? o[m] : 0x7fffffff;

  // ---- hot loop: R0 verbatim ----
  for (int i = 0; i < 8; ++i) {
    const int row0 = rows0 + i * 16;
    half8 a0, a1;
    a0[0] = (_Float16)f0.x; a0[1] = (_Float16)f0.y;
    a0[2] = (_Float16)f0.z; a0[3] = (_Float16)f0.w;
    a0[4] = (_Float16)f1.x; a0[5] = (_Float16)f1.y;
    a0[6] = (_Float16)f1.z; a0[7] = (_Float16)f1.w;
    a1[0] = (_Float16)f2.x; a1[1] = (_Float16)f2.y;
    a1[2] = (_Float16)f2.z; a1[3] = (_Float16)f2.w;
    a1[4] = (_Float16)f3.x; a1[5] = (_Float16)f3.y;
    a1[6] = (_Float16)f3.z; a1[7] = (_Float16)f3.w;

    if (i < 7) {  // prefetch next tile while MFMA+stores run
      const float* p = x + (size_t)(row0 + 16 + m) * 64 + quad * 8;
      f0 = *(const float4*)(p + 0);
      f1 = *(const float4*)(p + 4);
      f2 = *(const float4*)(p + 32);
      f3 = *(const float4*)(p + 36);
    }

    // segment of this 16-row tile via ballot popcount (o in lanes 0..15)
    const int s0 = (int)__popcll(__ballot(row0 >= ov) & 0xFFFFull);
    const int s1 = (int)__popcll(__ballot(row0 + 15 >= ov) & 0xFFFFull);

    if (s0 == s1) {  // tile entirely in one segment (common)
      const float* bp = &bufA[s0 * 64 + m];
#pragma unroll
      for (int t = 0; t < 4; ++t) {
        float4v c = {0.f, 0.f, 0.f, 0.f};
        c = __builtin_amdgcn_mfma_f32_16x16x32_f16(a0, bfrag[t][0], c, 0, 0, 0);
        c = __builtin_amdgcn_mfma_f32_16x16x32_f16(a1, bfrag[t][1], c, 0, 0, 0);
        const float bv = bp[t * 16];
        float* op = out + (size_t)(row0 + quad * 4) * 64 + t * 16 + m;
#pragma unroll
        for (int rg = 0; rg < 4; ++rg)
          op[(size_t)rg * 64] = fmaxf(c[rg] + bv, 0.f);
      }
    } else {  // boundary tile (rare): per-row segment scan
#pragma unroll
      for (int t = 0; t < 4; ++t) {
        float4v c = {0.f, 0.f, 0.f, 0.f};
        c = __builtin_amdgcn_mfma_f32_16x16x32_f16(a0, bfrag[t][0], c, 0, 0, 0);
        c = __builtin_amdgcn_mfma_f32_16x16x32_f16(a1, bfrag[t][1], c, 0, 0, 0);
#pragma unroll
        for (int rg = 0; rg < 4; ++rg) {
          const int row = row0 + quad * 4 + rg;
          int s = 0;
          for (int q2 = 0; q2 < nB; ++q2) s += (row >= o[q2]) ? 1 : 0;
          const float bv = bufA[s * 64 + t * 16 + m];
          out[(size_t)row * 64 + t * 16 + m] = fmaxf(c[rg] + bv, 0.f);
        }
      }
    }
  }
}

// ---------------------------------------------------------------- launch
extern "C" void kernel_launch(void* const* d_in, const int* in_sizes, int n_in,
                              void* d_out, int out_size, void* d_ws, size_t ws_size,
                              hipStream_t stream) {
  const float* x     = (const float*)d_in[0];
  const int*   o     = (const int*)d_in[1];
  const float* W2    = (const float*)d_in[2];
  const float* b2    = (const float*)d_in[3];
  const float* W1    = (const float*)d_in[4];
  const float* b1    = (const float*)d_in[5];
  const float* gamma = (const float*)d_in[6];
  const float* beta  = (const float*)d_in[7];
  const float* rmean = (const float*)d_in[8];
  const float* rvar  = (const float*)d_in[9];
  float* out = (float*)d_out;

  const int npts = in_sizes[0] / 64;
  const int nB   = in_sizes[1];

  float* gsums = (float*)d_ws;  // [16*64] f32

  hipMemsetAsync(gsums, 0, MAXB * 64 * sizeof(float), stream);

  const int blocks1 = 2048;  // 512 pts/block at N=1M
  pool_kernel<<<blocks1, 256, 0, stream>>>(x, o, gsums, nB, npts / blocks1);
  main_kernel<<<npts / 512, 256, 0, stream>>>(
      x, o, W2, b2, W1, b1, gamma, beta, rmean, rvar, gsums, out, nB);
}

// Round 5
// 518.521 us; speedup vs baseline: 1.4802x; 1.0131x over previous
//
#include <hip/hip_runtime.h>

// TransitionUp: segment mean-pool -> linear2+ReLU (tiny) -> broadcast ->
// [x, h[seg]] @ W1 + b1 -> BN(eval) -> ReLU.
//
// Folded math:
//   a[j]     = gamma[j] * rsqrt(run_var[j]+eps)
//   d[j]     = beta[j] - run_mean[j]*a[j]
//   W'[k][j] = W1[k][j] * a[j]                  (k in 0..63, the x-half)
//   bias'[b][j] = (h[b]@W1[64:] + b1)[j]*a[j] + d[j]
//   out[p][j] = relu( x[p]@W'[:,j] + bias'[seg(p)][j] )
//
// Session ledger:
// R2: main = MFMA f16 16x16x32, NO LDS; B pinned in 32 VGPRs.  -> 521.97us
// R3: LLC games (reverse rescan + NT out) exactly neutral.
// R4: f16 z-roundtrip REGRESSED +36us (NT x loads on gappy 16B pattern
//     defeat line reuse). NT only on contiguous streams. Pooling-via-
//     shfl_xor path in R4 PASSED -> correctness-proven.
// R5: per-block __threadfence() catastrophic (+245us, TCC serialized).
//     GOLD: pool_R5=393 measured => healthy pool ~145us (1.85 TB/s
//     effective) vs main ~95us doing MORE traffic. Pool is latency/
//     occupancy-limited, not BW-limited. R5 pool VGPR=92 -> 4 waves/SIMD.
// R6: mid-dispatch removal neutral (+3): dispatch count off critical path.
// R7 (this round): pool rewritten with main's proven load pipeline
//     (explicit prefetch-next-tile software pipeline, 16B x4 per lane) +
//     R4's proven shfl_xor m-lane reduction + __launch_bounds__(256,8)
//     to pin <=64 VGPR / 8 blocks/CU. mid & main restored to the R0
//     521.97us twins VERBATIM so delta-dur == delta-pool.
//     Predict: pool 145 -> ~55; dur 522 -> ~435. If dur ~522: pool-145
//     inference falsified -> ROOFLINE.

#define MAXB 16

typedef _Float16 half8 __attribute__((ext_vector_type(8)));
typedef float float4v __attribute__((ext_vector_type(4)));

// ---------------------------------------------------------------- kernel 1
// Per-segment column sums of x into gsums[B][64] (pre-zeroed via memset).
// v2: main-style software-pipelined loads. Each wave: 128 rows as 8 tiles
// of 16; lane (quad,m) reads row tile+m, float bytes quad*32..+32 and
// 128+quad*32..+32 (16B x4). Accumulate in 4 float4 chains; reduce over the
// 16 m-lanes via shfl_xor (stays in quad); cross-wave via tiny LDS; one
// 64-lane atomicAdd per block. Boundary blocks (15 of 2048) keep the old
// per-point binning path.
__global__ __launch_bounds__(256, 8) void pool_kernel(
    const float* __restrict__ x, const int* __restrict__ o,
    float* __restrict__ gsums, int nB, int ptsPerBlock) {
  __shared__ int so_s[MAXB];
  __shared__ float red[4 * 64];       // cross-wave reduction scratch
  __shared__ float ssum2[MAXB * 64];  // boundary-path bins
  const int tid = threadIdx.x;
  if (tid < nB) so_s[tid] = o[tid];
  __syncthreads();

  const int lane = tid & 63;
  const int m = lane & 15;
  const int quad = lane >> 4;
  const int w = tid >> 6;
  const int p0 = blockIdx.x * ptsPerBlock;
  const int rows0 = p0 + w * 128;

  int sFirst = 0;
  while (p0 >= so_s[sFirst]) sFirst++;
  int sLast = sFirst;
  while (p0 + ptsPerBlock - 1 >= so_s[sLast]) sLast++;

  if (sFirst == sLast) {  // block-uniform branch (2033 of 2048 blocks)
    float4v s0 = {0.f, 0.f, 0.f, 0.f}, s1 = s0, s2 = s0, s3 = s0;

    float4v f0, f1, f2, f3;  // staged tile (this lane: 16 floats of 16 rows)
    {
      const float* p = x + (size_t)(rows0 + m) * 64 + quad * 8;
      f0 = *(const float4v*)(p + 0);
      f1 = *(const float4v*)(p + 4);
      f2 = *(const float4v*)(p + 32);
      f3 = *(const float4v*)(p + 36);
    }

    for (int i = 0; i < 8; ++i) {
      s0 += f0; s1 += f1; s2 += f2; s3 += f3;
      if (i < 7) {  // prefetch next 16-row tile (independent of the adds)
        const float* p = x + (size_t)(rows0 + (i + 1) * 16 + m) * 64 + quad * 8;
        f0 = *(const float4v*)(p + 0);
        f1 = *(const float4v*)(p + 4);
        f2 = *(const float4v*)(p + 32);
        f3 = *(const float4v*)(p + 36);
      }
    }

    // reduce over the 16 m-lanes (lane bits 0..3; stays within quad group)
#pragma unroll
    for (int mask = 1; mask < 16; mask <<= 1) {
#pragma unroll
      for (int k = 0; k < 4; ++k) {
        s0[k] += __shfl_xor(s0[k], mask);
        s1[k] += __shfl_xor(s1[k], mask);
        s2[k] += __shfl_xor(s2[k], mask);
        s3[k] += __shfl_xor(s3[k], mask);
      }
    }
    if (m == 0) {  // lane quad*16: cols quad*8+0..7 and 32+quad*8+0..7
      *(float4v*)&red[w * 64 + quad * 8 + 0] = s0;
      *(float4v*)&red[w * 64 + quad * 8 + 4] = s1;
      *(float4v*)&red[w * 64 + 32 + quad * 8 + 0] = s2;
      *(float4v*)&red[w * 64 + 32 + quad * 8 + 4] = s3;
    }
    __syncthreads();
    if (tid < 64) {
      float s = red[tid] + red[64 + tid] + red[128 + tid] + red[192 + tid];
      atomicAdd(&gsums[sFirst * 64 + tid], s);
    }
  } else {  // boundary block (rare): per-point binning (R0 verbatim)
    const int c4 = (tid & 15) * 4;
    const int r  = tid >> 4;
    const int iters = ptsPerBlock >> 4;
    for (int i = tid; i < nB * 64; i += 256) ssum2[i] = 0.f;
    __syncthreads();
    for (int i = 0; i < iters; ++i) {
      int p = p0 + i * 16 + r;
      int s = 0;
      while (p >= so_s[s]) s++;
      float4 v = *(const float4*)(x + (size_t)p * 64 + c4);
      atomicAdd(&ssum2[s * 64 + c4 + 0], v.x);
      atomicAdd(&ssum2[s * 64 + c4 + 1], v.y);
      atomicAdd(&ssum2[s * 64 + c4 + 2], v.z);
      atomicAdd(&ssum2[s * 64 + c4 + 3], v.w);
    }
    __syncthreads();
    for (int i = tid; i < nB * 64; i += 256) {
      float v = ssum2[i];
      if (v != 0.f) atomicAdd(&gsums[i], v);
    }
  }
}

// ---------------------------------------------------------------- kernel 2
// mean -> h = relu(mean@W2+b2) -> bias'[b][j]; WpT[j][k] = f16(W1[k][j]*a[j]).
// R0 verbatim (the 521.97us twin).
__global__ __launch_bounds__(256) void mid_kernel(
    const float* __restrict__ gsums, const int* __restrict__ o,
    const float* __restrict__ W2, const float* __restrict__ b2,
    const float* __restrict__ W1, const float* __restrict__ b1,
    const float* __restrict__ gamma, const float* __restrict__ beta,
    const float* __restrict__ rmean, const float* __restrict__ rvar,
    float* __restrict__ biasp, _Float16* __restrict__ WpT, int nB) {
  __shared__ float smean[MAXB * 64];
  __shared__ float sh[MAXB * 64];
  const int tid = threadIdx.x;
  const int j = tid & 63;
  const int bq = tid >> 6;

  for (int i = tid; i < nB * 64; i += 256) {
    int b = i >> 6;
    int cnt = o[b] - (b ? o[b - 1] : 0);
    smean[i] = gsums[i] / (float)cnt;
  }
  __syncthreads();

  for (int b = bq; b < nB; b += 4) {
    float p0 = 0.f, p1 = 0.f, p2 = 0.f, p3 = 0.f;  // 4 chains for ILP
#pragma unroll
    for (int c = 0; c < 64; c += 4) {
      p0 = fmaf(smean[b * 64 + c + 0], W2[(c + 0) * 64 + j], p0);
      p1 = fmaf(smean[b * 64 + c + 1], W2[(c + 1) * 64 + j], p1);
      p2 = fmaf(smean[b * 64 + c + 2], W2[(c + 2) * 64 + j], p2);
      p3 = fmaf(smean[b * 64 + c + 3], W2[(c + 3) * 64 + j], p3);
    }
    sh[b * 64 + j] = fmaxf(((p0 + p1) + (p2 + p3)) + b2[j], 0.f);
  }
  __syncthreads();

  const float a = gamma[j] * rsqrtf(rvar[j] + 1e-5f);
  const float d = beta[j] - rmean[j] * a;
  for (int b = bq; b < nB; b += 4) {
    float p0 = 0.f, p1 = 0.f, p2 = 0.f, p3 = 0.f;
#pragma unroll
    for (int c = 0; c < 64; c += 4) {
      p0 = fmaf(sh[b * 64 + c + 0], W1[(64 + c + 0) * 64 + j], p0);
      p1 = fmaf(sh[b * 64 + c + 1], W1[(64 + c + 1) * 64 + j], p1);
      p2 = fmaf(sh[b * 64 + c + 2], W1[(64 + c + 2) * 64 + j], p2);
      p3 = fmaf(sh[b * 64 + c + 3], W1[(64 + c + 3) * 64 + j], p3);
    }
    biasp[b * 64 + j] = (((p0 + p1) + (p2 + p3)) + b1[j]) * a + d;
  }
  for (int k = bq * 16; k < bq * 16 + 16; ++k)
    WpT[j * 64 + k] = (_Float16)(W1[k * 64 + j] * a);
}

// ---------------------------------------------------------------- kernel 3
// Each wave: 8 row-tiles of 16 points, 4 col-tiles of 16. No LDS, no barrier.
// R0 verbatim (the 521.97us twin).
__global__ __launch_bounds__(256) void main_kernel(
    const float* __restrict__ x, const int* __restrict__ o,
    const _Float16* __restrict__ WpT, const float* __restrict__ biasp,
    float* __restrict__ out, int nB) {
  const int lane = threadIdx.x & 63;
  const int m = lane & 15;
  const int quad = lane >> 4;
  const int rows0 = (blockIdx.x * 4 + (threadIdx.x >> 6)) * 128;

  // B = W' pinned in registers: 4 col-tiles x 2 K-halves x 8 f16
  half8 bfrag[4][2];
#pragma unroll
  for (int t = 0; t < 4; ++t)
#pragma unroll
    for (int h = 0; h < 2; ++h)
      bfrag[t][h] = *(const half8*)(WpT + (t * 16 + m) * 64 + h * 32 + quad * 8);

  // lane m holds o[m] for ballot-based segment lookup
  const int ov = (m < nB) ? o[m] : 0x7fffffff;

  float4 f0, f1, f2, f3;  // fp32 staging for one 16x64 A-tile (this lane: 16 floats)
  {
    const float* p = x + (size_t)(rows0 + m) * 64 + quad * 8;
    f0 = *(const float4*)(p + 0);
    f1 = *(const float4*)(p + 4);
    f2 = *(const float4*)(p + 32);
    f3 = *(const float4*)(p + 36);
  }

  for (int i = 0; i < 8; ++i) {
    const int row0 = rows0 + i * 16;
    // cvt staging -> f16 fragments (k 0..31 and 32..63)
    half8 a0, a1;
    a0[0] = (_Float16)f0.x; a0[1] = (_Float16)f0.y;
    a0[2] = (_Float16)f0.z; a0[3] = (_Float16)f0.w;
    a0[4] = (_Float16)f1.x; a0[5] = (_Float16)f1.y;
    a0[6] = (_Float16)f1.z; a0[7] = (_Float16)f1.w;
    a1[0] = (_Float16)f2.x; a1[1] = (_Float16)f2.y;
    a1[2] = (_Float16)f2.z; a1[3] = (_Float16)f2.w;
    a1[4] = (_Float16)f3.x; a1[5] = (_Float16)f3.y;
    a1[6] = (_Float16)f3.z; a1[7] = (_Float16)f3.w;

    if (i < 7) {  // prefetch next tile while MFMA+stores run
      const float* p = x + (size_t)(row0 + 16 + m) * 64 + quad * 8;
      f0 = *(const float4*)(p + 0);
      f1 = *(const float4*)(p + 4);
      f2 = *(const float4*)(p + 32);
      f3 = *(const float4*)(p + 36);
    }

    // segment of this 16-row tile via ballot popcount (o in lanes 0..15)
    const int s0 = (int)__popcll(__ballot(row0 >= ov) & 0xFFFFull);
    const int s1 = (int)__popcll(__ballot(row0 + 15 >= ov) & 0xFFFFull);

    if (s0 == s1) {  // tile entirely in one segment (common)
      const float* bp = biasp + s0 * 64 + m;
#pragma unroll
      for (int t = 0; t < 4; ++t) {
        float4v c = {0.f, 0.f, 0.f, 0.f};
        c = __builtin_amdgcn_mfma_f32_16x16x32_f16(a0, bfrag[t][0], c, 0, 0, 0);
        c = __builtin_amdgcn_mfma_f32_16x16x32_f16(a1, bfrag[t][1], c, 0, 0, 0);
        const float bv = bp[t * 16];
        float* op = out + (size_t)(row0 + quad * 4) * 64 + t * 16 + m;
#pragma unroll
        for (int rg = 0; rg < 4; ++rg)
          op[(size_t)rg * 64] = fmaxf(c[rg] + bv, 0.f);
      }
    } else {  // boundary tile (rare): per-row segment scan
#pragma unroll
      for (int t = 0; t < 4; ++t) {
        float4v c = {0.f, 0.f, 0.f, 0.f};
        c = __builtin_amdgcn_mfma_f32_16x16x32_f16(a0, bfrag[t][0], c, 0, 0, 0);
        c = __builtin_amdgcn_mfma_f32_16x16x32_f16(a1, bfrag[t][1], c, 0, 0, 0);
#pragma unroll
        for (int rg = 0; rg < 4; ++rg) {
          const int row = row0 + quad * 4 + rg;
          int s = 0;
          for (int q2 = 0; q2 < nB; ++q2) s += (row >= o[q2]) ? 1 : 0;
          const float bv = biasp[s * 64 + t * 16 + m];
          out[(size_t)row * 64 + t * 16 + m] = fmaxf(c[rg] + bv, 0.f);
        }
      }
    }
  }
}

// ---------------------------------------------------------------- launch
extern "C" void kernel_launch(void* const* d_in, const int* in_sizes, int n_in,
                              void* d_out, int out_size, void* d_ws, size_t ws_size,
                              hipStream_t stream) {
  const float* x     = (const float*)d_in[0];
  const int*   o     = (const int*)d_in[1];
  const float* W2    = (const float*)d_in[2];
  const float* b2    = (const float*)d_in[3];
  const float* W1    = (const float*)d_in[4];
  const float* b1    = (const float*)d_in[5];
  const float* gamma = (const float*)d_in[6];
  const float* beta  = (const float*)d_in[7];
  const float* rmean = (const float*)d_in[8];
  const float* rvar  = (const float*)d_in[9];
  float* out = (float*)d_out;

  const int npts = in_sizes[0] / 64;
  const int nB   = in_sizes[1];

  float*    gsums = (float*)d_ws;                    // [16*64] f32
  float*    biasp = gsums + MAXB * 64;               // [16*64] f32
  _Float16* WpT   = (_Float16*)(biasp + MAXB * 64);  // [64*64] f16 (16B-aligned)

  hipMemsetAsync(gsums, 0, MAXB * 64 * sizeof(float), stream);

  const int blocks1 = 2048;                          // 512 pts/block at N=1M
  pool_kernel<<<blocks1, 256, 0, stream>>>(x, o, gsums, nB, npts / blocks1);
  mid_kernel<<<1, 256, 0, stream>>>(gsums, o, W2, b2, W1, b1, gamma, beta,
                                    rmean, rvar, biasp, WpT, nB);
  main_kernel<<<npts / 512, 256, 0, stream>>>(x, o, WpT, biasp, out, nB);
}